// Round 3
// baseline (499.689 us; speedup 1.0000x reference)
//
#include <hip/hip_runtime.h>

// LSTM-GCN single step from (H=0, C=0).
// Collapsed math: Fg gate dead (C_prev=0), cheb(H,..)=bh, peephole wc[0],wc[1] dead.
// Stages: zero -> deg -> dinv -> scatter(tx1 = L_hat @ x) -> gates+epilogue.
//
// NOTE: harness passes ALL integer inputs as int32 ("integer -> const int*").
// Rounds 1-2 crashed by casting edge_index to long long (garbage indices -> OOB
// atomics -> memory fault). edge_index is const int*.

#define FDIM 32
#define MAX_N 100000

__device__ float g_deg[MAX_N];            // degree -> dinv in place
__device__ float g_tx1[MAX_N * FDIM];     // L_hat @ x

__global__ void zero_kernel(int n_nodes) {
    int i = blockIdx.x * blockDim.x + threadIdx.x;
    int tot = n_nodes * (FDIM + 1);
    for (; i < tot; i += gridDim.x * blockDim.x) {
        if (i < n_nodes) g_deg[i] = 0.f;
        else             g_tx1[i - n_nodes] = 0.f;
    }
}

__global__ void deg_kernel(const int* __restrict__ ei,
                           const float* __restrict__ w, int E, int n_nodes) {
    int e = blockIdx.x * blockDim.x + threadIdx.x;
    if (e >= E) return;
    int s = ei[e];
    int d = ei[E + e];
    if (s == d) return;                 // self-loop weight zeroed
    if ((unsigned)s >= (unsigned)n_nodes || (unsigned)d >= (unsigned)n_nodes) return;
    unsafeAtomicAdd(&g_deg[s], w[e]);
}

__global__ void dinv_kernel(int n) {
    int i = blockIdx.x * blockDim.x + threadIdx.x;
    if (i >= n) return;
    float d = g_deg[i];
    g_deg[i] = (d > 0.f) ? rsqrtf(d) : 0.f;
}

// One half-wave (32 lanes) per edge: lane f handles feature f.
// tx1[dst] += (-dinv[src]*w*dinv[dst]) * x[src]
__global__ void scatter_kernel(const int* __restrict__ ei,
                               const float* __restrict__ w,
                               const float* __restrict__ x, int E, int n_nodes) {
    int t = blockIdx.x * blockDim.x + threadIdx.x;
    int e = t >> 5;
    int f = t & 31;
    if (e >= E) return;
    int s = ei[e];
    int d = ei[E + e];
    if (s == d) return;
    if ((unsigned)s >= (unsigned)n_nodes || (unsigned)d >= (unsigned)n_nodes) return;
    float nrm = -g_deg[s] * w[e] * g_deg[d];   // g_deg holds dinv now
    float xv = x[s * FDIM + f];
    unsafeAtomicAdd(&g_tx1[d * FDIM + f], nrm * xv);
}

// 8 nodes per 256-thread block; thread (node, j) computes output feature j of
// gates i, c, o. Weights for the 3 live gates staged in LDS (24 KB).
__global__ __launch_bounds__(256) void gates_kernel(
    const float* __restrict__ x,
    const float* __restrict__ Wx, const float* __restrict__ bx,
    const float* __restrict__ bh, const float* __restrict__ wc,
    const float* __restrict__ bg, const float* __restrict__ lin_w,
    const float* __restrict__ lin_b, float* __restrict__ out, int n_nodes) {
    __shared__ float Ws[3 * 2048];      // gates {i,c,o} x K=2 x 32x32
    __shared__ float xs[8 * FDIM];
    __shared__ float ts[8 * FDIM];

    // local gate -> global gate row in Wx (4,2,32,32): i=0, c=2, o=3
    for (int idx = threadIdx.x; idx < 2048; idx += 256) {
        Ws[idx]          = Wx[0 * 2048 + idx];
        Ws[2048 + idx]   = Wx[2 * 2048 + idx];
        Ws[4096 + idx]   = Wx[3 * 2048 + idx];
    }
    int node0 = blockIdx.x * 8;
    {
        int n = node0 + (threadIdx.x >> 5);
        int f = threadIdx.x & 31;
        if (n < n_nodes) {
            xs[threadIdx.x] = x[n * FDIM + f];
            ts[threadIdx.x] = g_tx1[n * FDIM + f];
        }
    }
    __syncthreads();

    int ln = threadIdx.x >> 5;
    int j  = threadIdx.x & 31;
    int n  = node0 + ln;
    if (n >= n_nodes) return;

    const float* xr = &xs[ln * FDIM];
    const float* tr = &ts[ln * FDIM];
    float acc_i = 0.f, acc_c = 0.f, acc_o = 0.f;
#pragma unroll
    for (int k = 0; k < 32; ++k) {
        float xv = xr[k], tv = tr[k];
        int o0 = k * 32 + j;
        acc_i += xv * Ws[o0]          + tv * Ws[1024 + o0];
        acc_c += xv * Ws[2048 + o0]   + tv * Ws[3072 + o0];
        acc_o += xv * Ws[4096 + o0]   + tv * Ws[5120 + o0];
    }
    float bi = bx[0 * 32 + j] + bh[0 * 32 + j] + bg[0 * 32 + j];
    float bc = bx[2 * 32 + j] + bh[2 * 32 + j] + bg[2 * 32 + j];
    float bo = bx[3 * 32 + j] + bh[3 * 32 + j] + bg[3 * 32 + j];

    float I = 1.f / (1.f + __expf(-(acc_i + bi)));
    float T = tanhf(acc_c + bc);
    float C = I * T;                                    // Fg*C_prev = 0
    float O = 1.f / (1.f + __expf(-(acc_o + bo + wc[2 * 32 + j] * C)));
    float H = O * tanhf(C);
    float r = fmaxf(H, 0.f) * lin_w[j];
#pragma unroll
    for (int m = 16; m > 0; m >>= 1) r += __shfl_xor(r, m, 32);
    if (j == 0) out[n] = r + lin_b[0];
}

extern "C" void kernel_launch(void* const* d_in, const int* in_sizes, int n_in,
                              void* d_out, int out_size, void* d_ws, size_t ws_size,
                              hipStream_t stream) {
    const float* x     = (const float*)d_in[0];
    const int*   ei    = (const int*)d_in[1];      // int32 on device (harness converts)
    const float* w     = (const float*)d_in[2];
    const float* Wx    = (const float*)d_in[3];
    const float* bx    = (const float*)d_in[4];
    // d_in[5] = Wh: unused (H=0)
    const float* bh    = (const float*)d_in[6];
    const float* wc    = (const float*)d_in[7];
    const float* bg    = (const float*)d_in[8];
    const float* lin_w = (const float*)d_in[9];
    const float* lin_b = (const float*)d_in[10];
    float*       out   = (float*)d_out;

    int n_nodes = in_sizes[0] / FDIM;
    if (n_nodes > MAX_N) n_nodes = MAX_N;   // static scratch bound (N=100000)
    const int E = in_sizes[2];

    zero_kernel<<<1024, 256, 0, stream>>>(n_nodes);
    deg_kernel<<<(E + 255) / 256, 256, 0, stream>>>(ei, w, E, n_nodes);
    dinv_kernel<<<(n_nodes + 255) / 256, 256, 0, stream>>>(n_nodes);
    {
        long long tot = (long long)E * 32;
        int blocks = (int)((tot + 255) / 256);
        scatter_kernel<<<blocks, 256, 0, stream>>>(ei, w, x, E, n_nodes);
    }
    gates_kernel<<<(n_nodes + 7) / 8, 256, 0, stream>>>(
        x, Wx, bx, bh, wc, bg, lin_w, lin_b, out, n_nodes);
}

// Round 4
// 478.995 us; speedup vs baseline: 1.0432x; 1.0432x over previous
//
#include <hip/hip_runtime.h>

// LSTM-GCN single step from (H=0, C=0).
// Collapsed math: Fg gate dead (C_prev=0), cheb(H,..)=bh, peephole wc[0],wc[1] dead.
//
// R4: replace the 51.2M-fp32-atomic scatter (242 us, atomic-pipe-bound: 0% MFMA,
// 13% VALU, 20% HBM, 250 MB write-through) with per-call counting sort by dst
// (CSR) + atomic-free gather. Edge index is int32 on device (harness converts).

#define FDIM 32
#define MAX_N 100000
#define MAX_E 1600000
#define SCAN_TILE 1024   // elements per scan block (256 thr x 4)

__device__ float g_deg[MAX_N];            // degree -> dinv in place
__device__ int   g_row[MAX_N + 1];        // counts -> exclusive row starts
__device__ int   g_cursor[MAX_N];         // fill cursors for reorder
__device__ int   g_blk[1024];             // scan block sums
__device__ int   g_src[MAX_E];            // CSR: src per edge, sorted by dst
__device__ float g_nrm[MAX_E];            // CSR: norm per edge, sorted by dst
__device__ float g_tx1[MAX_N * FDIM];     // L_hat @ x

__global__ void zero_kernel(int n_nodes) {
    int i = blockIdx.x * blockDim.x + threadIdx.x;
    for (; i < n_nodes; i += gridDim.x * blockDim.x) {
        g_deg[i] = 0.f;
        g_row[i] = 0;
    }
}

// deg[s] += w (self-loops excluded); row[d] += 1 (all edges kept; self-loops get nrm=0)
__global__ void count_deg_kernel(const int* __restrict__ ei,
                                 const float* __restrict__ w, int E, int n_nodes) {
    int e = blockIdx.x * blockDim.x + threadIdx.x;
    if (e >= E) return;
    int s = ei[e];
    int d = ei[E + e];
    if ((unsigned)s >= (unsigned)n_nodes || (unsigned)d >= (unsigned)n_nodes) return;
    if (s != d) unsafeAtomicAdd(&g_deg[s], w[e]);
    atomicAdd(&g_row[d], 1);
}

__global__ void dinv_kernel(int n) {
    int i = blockIdx.x * blockDim.x + threadIdx.x;
    if (i >= n) return;
    float d = g_deg[i];
    g_deg[i] = (d > 0.f) ? rsqrtf(d) : 0.f;
}

// --- exclusive scan over g_row[0..n), 3 kernels ---
__global__ __launch_bounds__(256) void scan1_kernel(int n) {
    __shared__ int sh[256];
    int tid = threadIdx.x;
    int base = blockIdx.x * SCAN_TILE + tid * 4;
    int v[4];
#pragma unroll
    for (int i = 0; i < 4; ++i) v[i] = (base + i < n) ? g_row[base + i] : 0;
    int tsum = v[0] + v[1] + v[2] + v[3];
    sh[tid] = tsum;
    __syncthreads();
    for (int off = 1; off < 256; off <<= 1) {
        int t = (tid >= off) ? sh[tid - off] : 0;
        __syncthreads();
        sh[tid] += t;
        __syncthreads();
    }
    if (tid == 255) g_blk[blockIdx.x] = sh[255];
    int run = sh[tid] - tsum;   // exclusive offset within block
#pragma unroll
    for (int i = 0; i < 4; ++i) {
        if (base + i < n) g_row[base + i] = run;
        run += v[i];
    }
}

__global__ __launch_bounds__(256) void scan2_kernel(int nb) {   // nb <= 1024
    __shared__ int sh[256];
    int tid = threadIdx.x;
    int base = tid * 4;
    int v[4];
#pragma unroll
    for (int i = 0; i < 4; ++i) v[i] = (base + i < nb) ? g_blk[base + i] : 0;
    int tsum = v[0] + v[1] + v[2] + v[3];
    sh[tid] = tsum;
    __syncthreads();
    for (int off = 1; off < 256; off <<= 1) {
        int t = (tid >= off) ? sh[tid - off] : 0;
        __syncthreads();
        sh[tid] += t;
        __syncthreads();
    }
    int run = sh[tid] - tsum;
#pragma unroll
    for (int i = 0; i < 4; ++i) {
        if (base + i < nb) g_blk[base + i] = run;
        run += v[i];
    }
}

__global__ void scan3_kernel(int n, int E) {
    int off = g_blk[blockIdx.x];
    int base = blockIdx.x * SCAN_TILE + threadIdx.x * 4;
#pragma unroll
    for (int i = 0; i < 4; ++i) {
        int idx = base + i;
        if (idx < n) {
            int v = g_row[idx] + off;
            g_row[idx] = v;
            g_cursor[idx] = v;
        }
    }
    if (blockIdx.x == 0 && threadIdx.x == 0) g_row[n] = E;
}

// scatter (src, nrm) into dst-sorted CSR slots
__global__ void reorder_kernel(const int* __restrict__ ei,
                               const float* __restrict__ w, int E, int n_nodes) {
    int e = blockIdx.x * blockDim.x + threadIdx.x;
    if (e >= E) return;
    int s = ei[e];
    int d = ei[E + e];
    if ((unsigned)s >= (unsigned)n_nodes || (unsigned)d >= (unsigned)n_nodes) return;
    float nrm = (s == d) ? 0.f : -g_deg[s] * w[e] * g_deg[d];   // g_deg holds dinv
    int pos = atomicAdd(&g_cursor[d], 1);
    g_src[pos] = s;
    g_nrm[pos] = nrm;
}

// half-wave (32 lanes = 32 features) per node; atomic-free accumulate
__global__ __launch_bounds__(256) void gather_kernel(const float* __restrict__ x,
                                                     int n_nodes) {
    int t = blockIdx.x * blockDim.x + threadIdx.x;
    int node = t >> 5;
    int f = t & 31;
    if (node >= n_nodes) return;
    int i = g_row[node];
    int end = g_row[node + 1];
    float acc = 0.f;
    for (; i + 4 <= end; i += 4) {
        int   s0 = g_src[i],     s1 = g_src[i + 1], s2 = g_src[i + 2], s3 = g_src[i + 3];
        float n0 = g_nrm[i],     n1 = g_nrm[i + 1], n2 = g_nrm[i + 2], n3 = g_nrm[i + 3];
        acc += n0 * x[s0 * FDIM + f] + n1 * x[s1 * FDIM + f]
             + n2 * x[s2 * FDIM + f] + n3 * x[s3 * FDIM + f];
    }
    for (; i < end; ++i) acc += g_nrm[i] * x[g_src[i] * FDIM + f];
    g_tx1[node * FDIM + f] = acc;
}

// 8 nodes per 256-thread block; thread (node, j) computes output feature j of
// gates i, c, o. Weights for the 3 live gates staged in LDS (24 KB).
__global__ __launch_bounds__(256) void gates_kernel(
    const float* __restrict__ x,
    const float* __restrict__ Wx, const float* __restrict__ bx,
    const float* __restrict__ bh, const float* __restrict__ wc,
    const float* __restrict__ bg, const float* __restrict__ lin_w,
    const float* __restrict__ lin_b, float* __restrict__ out, int n_nodes) {
    __shared__ float Ws[3 * 2048];      // gates {i,c,o} x K=2 x 32x32
    __shared__ float xs[8 * FDIM];
    __shared__ float ts[8 * FDIM];

    for (int idx = threadIdx.x; idx < 2048; idx += 256) {
        Ws[idx]          = Wx[0 * 2048 + idx];
        Ws[2048 + idx]   = Wx[2 * 2048 + idx];
        Ws[4096 + idx]   = Wx[3 * 2048 + idx];
    }
    int node0 = blockIdx.x * 8;
    {
        int n = node0 + (threadIdx.x >> 5);
        int f = threadIdx.x & 31;
        if (n < n_nodes) {
            xs[threadIdx.x] = x[n * FDIM + f];
            ts[threadIdx.x] = g_tx1[n * FDIM + f];
        }
    }
    __syncthreads();

    int ln = threadIdx.x >> 5;
    int j  = threadIdx.x & 31;
    int n  = node0 + ln;
    if (n >= n_nodes) return;

    const float* xr = &xs[ln * FDIM];
    const float* tr = &ts[ln * FDIM];
    float acc_i = 0.f, acc_c = 0.f, acc_o = 0.f;
#pragma unroll
    for (int k = 0; k < 32; ++k) {
        float xv = xr[k], tv = tr[k];
        int o0 = k * 32 + j;
        acc_i += xv * Ws[o0]          + tv * Ws[1024 + o0];
        acc_c += xv * Ws[2048 + o0]   + tv * Ws[3072 + o0];
        acc_o += xv * Ws[4096 + o0]   + tv * Ws[5120 + o0];
    }
    float bi = bx[0 * 32 + j] + bh[0 * 32 + j] + bg[0 * 32 + j];
    float bc = bx[2 * 32 + j] + bh[2 * 32 + j] + bg[2 * 32 + j];
    float bo = bx[3 * 32 + j] + bh[3 * 32 + j] + bg[3 * 32 + j];

    float I = 1.f / (1.f + __expf(-(acc_i + bi)));
    float T = tanhf(acc_c + bc);
    float C = I * T;                                    // Fg*C_prev = 0
    float O = 1.f / (1.f + __expf(-(acc_o + bo + wc[2 * 32 + j] * C)));
    float H = O * tanhf(C);
    float r = fmaxf(H, 0.f) * lin_w[j];
#pragma unroll
    for (int m = 16; m > 0; m >>= 1) r += __shfl_xor(r, m, 32);
    if (j == 0) out[n] = r + lin_b[0];
}

extern "C" void kernel_launch(void* const* d_in, const int* in_sizes, int n_in,
                              void* d_out, int out_size, void* d_ws, size_t ws_size,
                              hipStream_t stream) {
    const float* x     = (const float*)d_in[0];
    const int*   ei    = (const int*)d_in[1];      // int32 on device
    const float* w     = (const float*)d_in[2];
    const float* Wx    = (const float*)d_in[3];
    const float* bx    = (const float*)d_in[4];
    // d_in[5] = Wh: unused (H=0)
    const float* bh    = (const float*)d_in[6];
    const float* wc    = (const float*)d_in[7];
    const float* bg    = (const float*)d_in[8];
    const float* lin_w = (const float*)d_in[9];
    const float* lin_b = (const float*)d_in[10];
    float*       out   = (float*)d_out;

    int n_nodes = in_sizes[0] / FDIM;
    if (n_nodes > MAX_N) n_nodes = MAX_N;
    int E = in_sizes[2];
    if (E > MAX_E) E = MAX_E;

    int eb = (E + 255) / 256;
    int nb_scan = (n_nodes + SCAN_TILE - 1) / SCAN_TILE;   // 98 for N=100k

    zero_kernel<<<512, 256, 0, stream>>>(n_nodes);
    count_deg_kernel<<<eb, 256, 0, stream>>>(ei, w, E, n_nodes);
    dinv_kernel<<<(n_nodes + 255) / 256, 256, 0, stream>>>(n_nodes);
    scan1_kernel<<<nb_scan, 256, 0, stream>>>(n_nodes);
    scan2_kernel<<<1, 256, 0, stream>>>(nb_scan);
    scan3_kernel<<<nb_scan, 256, 0, stream>>>(n_nodes, E);
    reorder_kernel<<<eb, 256, 0, stream>>>(ei, w, E, n_nodes);
    {
        long long tot = (long long)n_nodes * 32;
        gather_kernel<<<(int)((tot + 255) / 256), 256, 0, stream>>>(x, n_nodes);
    }
    gates_kernel<<<(n_nodes + 7) / 8, 256, 0, stream>>>(
        x, Wx, bx, bh, wc, bg, lin_w, lin_b, out, n_nodes);
}